// Round 10
// baseline (708.640 us; speedup 1.0000x reference)
//
#include <hip/hip_runtime.h>
#include <stdint.h>

#define NPIX   (16 * 512 * 512)   // 4,194,304
#define IMG    (512 * 512)
#define NB     16
#define ITERS  200

#define CORE   64
#define HALO   8
#define KIT    8      // fused iterations per launch; 200 = 25 * 8
#define TBW    92     // boundary-row LDS stride (words); data at cols 4..83, sentinels at 3/84
#define TX0    4

#define BM_WORDS  (NPIX / 32)     // 131072 words = 512 KB per bitmap replica
#define NREP      16              // bitmap replicas (spread same-word atomics)
#define MAX3(a, b, c) max(max((a), (b)), (c))

// ---------- global max of predict (float4, 16 px/thread) ----------
__global__ __launch_bounds__(256) void k_max(const float4* __restrict__ p, unsigned int* umax) {
    unsigned int m = 0;
    int base = blockIdx.x * 1024;
#pragma unroll
    for (int k = 0; k < 4; ++k) {
        float4 v = p[base + k * 256 + threadIdx.x];
        m = max(m, __float_as_uint(v.x));
        m = max(m, __float_as_uint(v.y));
        m = max(m, __float_as_uint(v.z));
        m = max(m, __float_as_uint(v.w));
    }
    for (int o = 32; o > 0; o >>= 1)
        m = max(m, (unsigned int)__shfl_down(m, o, 64));
    __shared__ unsigned int sm[4];
    int lane = threadIdx.x & 63, w = threadIdx.x >> 6;
    if (lane == 0) sm[w] = m;
    __syncthreads();
    if (threadIdx.x == 0)
        atomicMax(umax, max(max(sm[0], sm[1]), max(sm[2], sm[3])));
}

// ---------- init labels + fused dice partials (float4, 16 px/thread) ----------
__global__ __launch_bounds__(256) void k_init(const float4* __restrict__ pr4,
                                              const float4* __restrict__ tg4,
                                              const unsigned int* __restrict__ umax,
                                              int4* __restrict__ lab4,
                                              float* __restrict__ num, float* __restrict__ den) {
    const float thr = __uint_as_float(*umax) * 0.5f;
    float sn = 0.f, sd = 0.f;
    int base = blockIdx.x * 1024;
#pragma unroll
    for (int k = 0; k < 4; ++k) {
        int i4 = base + k * 256 + threadIdx.x;
        float4 p = pr4[i4], t = tg4[i4];
        int pix = i4 * 4;
        int4 L;
        L.x = (p.x > thr) ? pix     : -1;
        L.y = (p.y > thr) ? pix + 1 : -1;
        L.z = (p.z > thr) ? pix + 2 : -1;
        L.w = (p.w > thr) ? pix + 3 : -1;
        lab4[i4] = L;
        sn += p.x * t.x + p.y * t.y + p.z * t.z + p.w * t.w;
        sd += p.x * p.x + p.y * p.y + p.z * p.z + p.w * p.w
            + t.x * t.x + t.y * t.y + t.z * t.z + t.w * t.w;
    }
    for (int o = 32; o > 0; o >>= 1) {
        sn += __shfl_down(sn, o, 64);
        sd += __shfl_down(sd, o, 64);
    }
    __shared__ float wn[4], wd[4];
    int lane = threadIdx.x & 63, w = threadIdx.x >> 6;
    if (lane == 0) { wn[w] = sn; wd[w] = sd; }
    __syncthreads();
    if (threadIdx.x == 0) {
        int b = blockIdx.x >> 6;
        atomicAdd(&num[b * 32], wn[0] + wn[1] + wn[2] + wn[3]);
        atomicAdd(&den[b * 32], wd[0] + wd[1] + wd[2] + wd[3]);
    }
}

// ---------- fused 8-iteration propagation: register strips + shuffle horizontal ----------
// Thread (cu,ru) owns rows yr..yr+7, cols x0..x0+3 in registers (O[8]).
// Horizontal neighbor cols come from __shfl of the prev-iter registers (west = tid-1,
// east = tid+1, same wave except 3 crossing pairs handled via tiny xw/xe LDS arrays;
// cu==0/19 get sentinel -1). Vertical boundary rows via Tb (full-width, sentinel cols).
__global__ __launch_bounds__(256, 4) void k_prop8(const int* __restrict__ in,
                                                  int* __restrict__ out) {
    __shared__ int Tb[22 * TBW];
    __shared__ int xw[3 * 8];   // O[j].w of tids 63,127,191  -> read by 64,128,192
    __shared__ int xe[3 * 8];   // O[j].x of tids 64,128,192  -> read by 63,127,191
    const int tid  = threadIdx.x;
    const int bimg = blockIdx.z;
    const int gx0  = blockIdx.x * CORE - HALO;
    const int gy0  = blockIdx.y * CORE - HALO;
    const int* img = in + bimg * IMG;

    // sentinels: Tb slots 0/21 full width; sentinel cols 3 and 84 of every slot
    if (tid < TBW) { Tb[tid] = -1; Tb[21 * TBW + tid] = -1; }
    if (tid < 22)  { Tb[tid * TBW + 3] = -1; Tb[tid * TBW + 84] = -1; }

    const bool active = (tid < 200);    // 20 col-units x 10 row-units
    const int cu = tid % 20, ru = tid / 20;
    const int lane = tid & 63, wav = tid >> 6;
    const int x0 = cu * 4;
    const int yr = ru * 8;
    const int gx = gx0 + x0;
    int4 O[8], M[8];

    __syncthreads();

#define GROW(row, V, VL, VR) do {                                              \
        int _gy = gy0 + (row);                                                 \
        if (_gy >= 0 && _gy < 512) {                                           \
            const int* _p = img + (_gy << 9);                                  \
            V  = (gx >= 0 && gx <= 508) ? *(const int4*)(_p + gx)              \
                                        : make_int4(-1, -1, -1, -1);           \
            VL = (gx - 1 >= 0 && gx - 1 < 512) ? _p[gx - 1] : -1;              \
            VR = (gx + 4 >= 0 && gx + 4 < 512) ? _p[gx + 4] : -1;              \
        } else { V = make_int4(-1, -1, -1, -1); VL = -1; VR = -1; }            \
    } while (0)

#define STEPM(j) do {                                                          \
        int4 col;                                                              \
        col.x = MAX3(A.x, B.x, C.x);                                           \
        col.y = MAX3(A.y, B.y, C.y);                                           \
        col.z = MAX3(A.z, B.z, C.z);                                           \
        col.w = MAX3(A.w, B.w, C.w);                                           \
        int cl = MAX3(Al, Bl, Cl);                                             \
        int cr = MAX3(Ar, Br, Cr);                                             \
        int4 n;                                                                \
        n.x = MAX3(cl,    col.x, col.y) | M[j].x;   /* bg stays -1 */          \
        n.y = MAX3(col.x, col.y, col.z) | M[j].y;                              \
        n.z = MAX3(col.y, col.z, col.w) | M[j].z;                              \
        n.w = MAX3(col.z, col.w, cr)    | M[j].w;                              \
        A = B; Al = Bl; Ar = Br;                                               \
        B = C; Bl = Cl; Br = Cr;                                               \
        O[j] = n;                                                              \
    } while (0)

#define PUBLISH() do {                                                         \
        if (active) {                                                          \
            *(int4*)&Tb[(2 * ru + 1) * TBW + TX0 + x0] = O[0];                 \
            *(int4*)&Tb[(2 * ru + 2) * TBW + TX0 + x0] = O[7];                 \
        }                                                                      \
        if (lane == 63 && wav < 3) {                                           \
            _Pragma("unroll")                                                  \
            for (int j = 0; j < 8; ++j) xw[wav * 8 + j] = O[j].w;              \
        }                                                                      \
        if (lane == 0 && wav > 0 && active) {                                  \
            _Pragma("unroll")                                                  \
            for (int j = 0; j < 8; ++j) xe[(wav - 1) * 8 + j] = O[j].x;        \
        }                                                                      \
    } while (0)

    // ---- iter 0: field from global; capture iteration-invariant mask ----
    if (active) {
        int4 A, B, C; int Al, Ar, Bl, Br, Cl, Cr;
        GROW(yr - 1, A, Al, Ar);
        GROW(yr,     B, Bl, Br);
#pragma unroll
        for (int j = 0; j < 8; ++j) {
            GROW(yr + j + 1, C, Cl, Cr);
            M[j].x = B.x >> 31;
            M[j].y = B.y >> 31;
            M[j].z = B.z >> 31;
            M[j].w = B.w >> 31;
            STEPM(j);
        }
    }
    PUBLISH();
    __syncthreads();

    // ---- iters 1..7 ----
    for (int it = 1; it < KIT; ++it) {
        int4 A, C8; int Al, Ar, C8l, C8r;
        if (active) {
            const int* tb0 = &Tb[(2 * ru) * TBW + TX0 + x0];
            A  = *(const int4*)tb0;  Al  = tb0[-1];  Ar  = tb0[4];
            const int* tb3 = &Tb[(2 * ru + 3) * TBW + TX0 + x0];
            C8 = *(const int4*)tb3;  C8l = tb3[-1];  C8r = tb3[4];
        }
        // horizontal neighbor cols from prev-iter registers
        int wl[8], wr[8];
#pragma unroll
        for (int j = 0; j < 8; ++j) {
            wl[j] = __shfl_up(O[j].w, 1, 64);
            wr[j] = __shfl_down(O[j].x, 1, 64);
        }
        if (lane == 0 && wav > 0) {
#pragma unroll
            for (int j = 0; j < 8; ++j) wl[j] = xw[(wav - 1) * 8 + j];
        }
        if (cu == 0) {
#pragma unroll
            for (int j = 0; j < 8; ++j) wl[j] = -1;
        }
        if (lane == 63 && wav < 3) {
#pragma unroll
            for (int j = 0; j < 8; ++j) wr[j] = xe[wav * 8 + j];
        }
        if (cu == 19) {
#pragma unroll
            for (int j = 0; j < 8; ++j) wr[j] = -1;
        }
        if (active) {
            int4 B = O[0], C;
            int Bl = wl[0], Br = wr[0], Cl, Cr;
#pragma unroll
            for (int j = 0; j < 8; ++j) {
                C  = (j < 7) ? O[j + 1] : C8;
                Cl = (j < 7) ? wl[j + 1] : C8l;
                Cr = (j < 7) ? wr[j + 1] : C8r;
                STEPM(j);
            }
        }
        if (it < KIT - 1) {                // last iteration's publish is dead
            __syncthreads();               // WAR: all Tb/xw/xe reads done
            PUBLISH();
            __syncthreads();               // RAW: publish visible
        }
    }

    // ---- write 64x64 core to global from registers ----
    if (active && ru >= 1 && ru <= 8 && cu >= 2 && cu <= 17) {
        int* oimg = out + bimg * IMG;
        int gyb = blockIdx.y * CORE + (yr - HALO);
        int gxo = blockIdx.x * CORE + (x0 - HALO);
#pragma unroll
        for (int j = 0; j < 8; ++j)
            *(int4*)(oimg + ((gyb + j) << 9) + gxo) = O[j];
    }
#undef GROW
#undef STEPM
#undef PUBLISH
}

// ---------- presence bitmap: 16 px/thread, 4 dedup phases, x16 replicas ----------
__global__ __launch_bounds__(256) void k_bits(const int* __restrict__ lab,
                                              unsigned int* __restrict__ bm) {
    __shared__ unsigned int sk[1024];   // SoA: sk[j*256 + tid]
    __shared__ int slot[256];
    const int tid = threadIdx.x;
    unsigned int* rep = bm + (blockIdx.x & (NREP - 1)) * BM_WORDS;
    for (int k = 0; k < 4; ++k) {
        if (k) __syncthreads();                       // WAR on sk/slot reuse
        const int i4 = blockIdx.x * 1024 + k * 256 + tid;
        int4 c = ((const int4*)lab)[i4];
        int pw = __shfl_up(c.w, 1, 64);
        unsigned int prevk;
        if ((tid & 63) == 0) {
            if (i4 == 0) prevk = ~0u;
            else { int pv = lab[i4 * 4 - 1]; prevk = (pv < 0) ? 0u : (unsigned int)pv; }
        } else {
            prevk = (pw < 0) ? 0u : (unsigned int)pw;
        }
        unsigned int k0 = (c.x < 0) ? 0u : (unsigned int)c.x;
        unsigned int k1 = (c.y < 0) ? 0u : (unsigned int)c.y;
        unsigned int k2 = (c.z < 0) ? 0u : (unsigned int)c.z;
        unsigned int k3 = (c.w < 0) ? 0u : (unsigned int)c.w;
        bool c0 = (k0 != prevk), c1 = (k1 != k0), c2 = (k2 != k1), c3 = (k3 != k2);
        sk[0 * 256 + tid] = k0;
        sk[1 * 256 + tid] = k1;
        sk[2 * 256 + tid] = k2;
        sk[3 * 256 + tid] = k3;
        if (c0) slot[k0 & 255] = tid * 4 + 0;
        if (c1) slot[k1 & 255] = tid * 4 + 1;
        if (c2) slot[k2 & 255] = tid * 4 + 2;
        if (c3) slot[k3 & 255] = tid * 4 + 3;
        __syncthreads();
#define SKAT(w) sk[((w) & 3) * 256 + ((w) >> 2)]
        if (c0) { int w = slot[k0 & 255]; if (w != tid * 4 + 0 && SKAT(w) == k0) c0 = false; }
        if (c1) { int w = slot[k1 & 255]; if (w != tid * 4 + 1 && SKAT(w) == k1) c1 = false; }
        if (c2) { int w = slot[k2 & 255]; if (w != tid * 4 + 2 && SKAT(w) == k2) c2 = false; }
        if (c3) { int w = slot[k3 & 255]; if (w != tid * 4 + 3 && SKAT(w) == k3) c3 = false; }
#undef SKAT
#define TSET(kk, cc) if (cc) {                                        \
            unsigned int word = rep[(kk) >> 5];                       \
            if (!((word >> ((kk) & 31)) & 1u))                        \
                atomicOr(&rep[(kk) >> 5], 1u << ((kk) & 31));         \
        }
        TSET(k0, c0); TSET(k1, c1); TSET(k2, c2); TSET(k3, c3);
#undef TSET
    }
}

// ---------- popcount reduce over OR of replicas ----------
__global__ void k_popc(const unsigned int* __restrict__ bm, unsigned int* nuniq, int words) {
    unsigned int c = 0;
    for (int i = blockIdx.x * blockDim.x + threadIdx.x; i < words; i += gridDim.x * blockDim.x) {
        unsigned int w = 0;
#pragma unroll
        for (int r = 0; r < NREP; ++r) w |= bm[r * BM_WORDS + i];
        c += __popc(w);
    }
    for (int o = 32; o > 0; o >>= 1)
        c += __shfl_down(c, o, 64);
    __shared__ unsigned int sc[4];
    int lane = threadIdx.x & 63, w = threadIdx.x >> 6;
    if (lane == 0) sc[w] = c;
    __syncthreads();
    if (threadIdx.x == 0)
        atomicAdd(nuniq, sc[0] + sc[1] + sc[2] + sc[3]);
}

// ---------- epilogue ----------
__global__ void k_final(const unsigned int* __restrict__ nuniq,
                        const float* __restrict__ num, const float* __restrict__ den,
                        float* __restrict__ out) {
    float loss = 0.0f;
    for (int b = 0; b < NB; ++b)
        loss += 1.0f - (num[b * 32] + 1.0f) / (den[b * 32] + 1.0f);
    loss *= (1.0f / NB);
    float penalty = (float)(*nuniq) / (float)NB;
    if (penalty < 1.0f) penalty = (float)NB;   // jnp.where(penalty < 1, B, penalty)
    penalty = fminf(penalty, (float)NB);       // jnp.minimum(penalty, B)
    out[0] = loss * penalty;
}

extern "C" void kernel_launch(void* const* d_in, const int* in_sizes, int n_in,
                              void* d_out, int out_size, void* d_ws, size_t ws_size,
                              hipStream_t stream) {
    const float* predict = (const float*)d_in[0];
    const float* target  = (const float*)d_in[1];
    float* out = (float*)d_out;

    // workspace layout (disjoint regions):
    //   +0    : umax, nuniq
    //   +256  : num[512]  (slot b*32, one 128B line per batch)
    //   +2304 : den[512]
    //   +16384: labA (16 MB) | labB (16 MB); bm replicas alias labA after prop
    char* ws = (char*)d_ws;
    unsigned int* umax  = (unsigned int*)ws;
    unsigned int* nuniq = (unsigned int*)(ws + 4);
    float* num = (float*)(ws + 256);
    float* den = (float*)(ws + 2304);
    int* labA = (int*)(ws + 16384);
    int* labB = labA + NPIX;
    unsigned int* bm = (unsigned int*)labA;   // reuse labA after prop (8 MB)

    hipMemsetAsync(ws, 0, 16384, stream);

    k_max<<<1024, 256, 0, stream>>>((const float4*)predict, umax);
    k_init<<<1024, 256, 0, stream>>>((const float4*)predict, (const float4*)target,
                                     umax, (int4*)labA, num, den);

    dim3 pb(256, 1, 1), pg(8, 8, 16);   // 64x64 core tiles
    int* a = labA;
    int* b = labB;
    for (int it = 0; it < ITERS / KIT; ++it) {   // 25 launches x 8 fused iters
        k_prop8<<<pg, pb, 0, stream>>>(a, b);
        int* t = a; a = b; b = t;
    }
    // 25 launches (odd) -> final labels in labB == a; labA free for bitmap
    hipMemsetAsync(bm, 0, (size_t)NREP * BM_WORDS * sizeof(unsigned int), stream);

    k_bits<<<NPIX / 4096, 256, 0, stream>>>(a, bm);
    k_popc<<<512, 256, 0, stream>>>(bm, nuniq, BM_WORDS);
    k_final<<<1, 1, 0, stream>>>(nuniq, num, den, out);
}

// Round 11
// 144.242 us; speedup vs baseline: 4.9129x; 4.9129x over previous
//
#include <hip/hip_runtime.h>
#include <hip/hip_cooperative_groups.h>
#include <stdint.h>

namespace cg = cooperative_groups;

#define NPIX   (16 * 512 * 512)   // 4,194,304
#define IMG    (512 * 512)
#define NB     16

#define CORE   64
#define HALO   8
#define KIT    8      // iterations per round; 200 = 25 * 8
#define NROUND 25
#define TILE   80     // fallback coop kernel: 64 core + 2*8 halo
#define TW     88     // padded tile row stride (words)
#define TH     82     // padded rows
#define TX0    4

#define BM_WORDS  (NPIX / 32)     // 131072 words = 512 KB per bitmap replica
#define NREP      16
#define SAT       256u            // iso_count >= SAT  =>  n_unique >= 256 => penalty == 16
#define MAX3(a, b, c) max(max((a), (b)), (c))

// ---------- global max of predict (float4, 16 px/thread) ----------
__global__ __launch_bounds__(256) void k_max(const float4* __restrict__ p, unsigned int* umax) {
    unsigned int m = 0;
    int base = blockIdx.x * 1024;
#pragma unroll
    for (int k = 0; k < 4; ++k) {
        float4 v = p[base + k * 256 + threadIdx.x];
        m = max(m, __float_as_uint(v.x));
        m = max(m, __float_as_uint(v.y));
        m = max(m, __float_as_uint(v.z));
        m = max(m, __float_as_uint(v.w));
    }
    for (int o = 32; o > 0; o >>= 1)
        m = max(m, (unsigned int)__shfl_down(m, o, 64));
    __shared__ unsigned int sm[4];
    int lane = threadIdx.x & 63, w = threadIdx.x >> 6;
    if (lane == 0) sm[w] = m;
    __syncthreads();
    if (threadIdx.x == 0)
        atomicMax(umax, max(max(sm[0], sm[1]), max(sm[2], sm[3])));
}

// ---------- init labels + fused dice partials (float4, 16 px/thread) ----------
__global__ __launch_bounds__(256) void k_init(const float4* __restrict__ pr4,
                                              const float4* __restrict__ tg4,
                                              const unsigned int* __restrict__ umax,
                                              int4* __restrict__ lab4,
                                              float* __restrict__ num, float* __restrict__ den) {
    const float thr = __uint_as_float(*umax) * 0.5f;
    float sn = 0.f, sd = 0.f;
    int base = blockIdx.x * 1024;
#pragma unroll
    for (int k = 0; k < 4; ++k) {
        int i4 = base + k * 256 + threadIdx.x;
        float4 p = pr4[i4], t = tg4[i4];
        int pix = i4 * 4;
        int4 L;
        L.x = (p.x > thr) ? pix     : -1;
        L.y = (p.y > thr) ? pix + 1 : -1;
        L.z = (p.z > thr) ? pix + 2 : -1;
        L.w = (p.w > thr) ? pix + 3 : -1;
        lab4[i4] = L;
        sn += p.x * t.x + p.y * t.y + p.z * t.z + p.w * t.w;
        sd += p.x * p.x + p.y * p.y + p.z * p.z + p.w * p.w
            + t.x * t.x + t.y * t.y + t.z * t.z + t.w * t.w;
    }
    for (int o = 32; o > 0; o >>= 1) {
        sn += __shfl_down(sn, o, 64);
        sd += __shfl_down(sd, o, 64);
    }
    __shared__ float wn[4], wd[4];
    int lane = threadIdx.x & 63, w = threadIdx.x >> 6;
    if (lane == 0) { wn[w] = sn; wd[w] = sd; }
    __syncthreads();
    if (threadIdx.x == 0) {
        int b = blockIdx.x >> 6;
        atomicAdd(&num[b * 32], wn[0] + wn[1] + wn[2] + wn[3]);
        atomicAdd(&den[b * 32], wd[0] + wd[1] + wd[2] + wd[3]);
    }
}

// ---------- count isolated masked pixels (id>0, no masked 8-neighbor) ----------
// Each such pixel keeps its unique id through ALL propagation iterations (values
// flow only via masked chains), so n_unique >= isoCnt. isoCnt >= 256 saturates
// the penalty clamp exactly at 16.0 for any input.
__global__ __launch_bounds__(256) void k_iso(const int* __restrict__ lab,
                                             unsigned int* __restrict__ isoCnt) {
    unsigned int cnt = 0;
    const int tid = threadIdx.x;
    for (int k = 0; k < 8; ++k) {                    // 512 blocks x 8 chunks x 256 thr
        int i4 = (blockIdx.x * 8 + k) * 256 + tid;   // int4 index
        int px = i4 * 4;
        int y = (px >> 9) & 511;
        int gxr = px & 511;
        int4 c = *(const int4*)(lab + px);
        int lc = (gxr > 0)   ? lab[px - 1] : -1;
        int rc = (gxr < 508) ? lab[px + 4] : -1;
        int4 u; int lu, ru;
        if (y > 0) {
            u  = *(const int4*)(lab + px - 512);
            lu = (gxr > 0)   ? lab[px - 513] : -1;
            ru = (gxr < 508) ? lab[px - 508] : -1;
        } else { u = make_int4(-1, -1, -1, -1); lu = -1; ru = -1; }
        int4 d; int ld, rd;
        if (y < 511) {
            d  = *(const int4*)(lab + px + 512);
            ld = (gxr > 0)   ? lab[px + 511] : -1;
            rd = (gxr < 508) ? lab[px + 516] : -1;
        } else { d = make_int4(-1, -1, -1, -1); ld = -1; rd = -1; }
        int v0 = max(u.x, d.x), v1 = max(u.y, d.y), v2 = max(u.z, d.z), v3 = max(u.w, d.w);
        int cmL = MAX3(lu, lc, ld), cmR = MAX3(ru, rc, rd);
        int cm0 = max(v0, c.x), cm1 = max(v1, c.y), cm2 = max(v2, c.z), cm3 = max(v3, c.w);
        int nb0 = MAX3(cmL, cm1, v0);   // max over 8 neighbors (excl. center)
        int nb1 = MAX3(cm0, cm2, v1);
        int nb2 = MAX3(cm1, cm3, v2);
        int nb3 = MAX3(cm2, cmR, v3);
        cnt += (c.x >= 0 && nb0 < 0 && px > 0) ? 1u : 0u;
        cnt += (c.y >= 0 && nb1 < 0) ? 1u : 0u;
        cnt += (c.z >= 0 && nb2 < 0) ? 1u : 0u;
        cnt += (c.w >= 0 && nb3 < 0) ? 1u : 0u;
    }
    for (int o = 32; o > 0; o >>= 1)
        cnt += __shfl_down(cnt, o, 64);
    __shared__ unsigned int sc[4];
    int lane = tid & 63, w = tid >> 6;
    if (lane == 0) sc[w] = cnt;
    __syncthreads();
    if (tid == 0)
        atomicAdd(isoCnt, sc[0] + sc[1] + sc[2] + sc[3]);
}

// ---------- FALLBACK: cooperative all-200-iteration propagation (R5, verified) ----------
// Only runs when isoCnt < 256 (unsaturated penalty). All blocks exit uniformly
// otherwise — no partial grid.sync.
__global__ __launch_bounds__(256, 4) void k_prop_all(int* __restrict__ bufA,
                                                     int* __restrict__ bufB,
                                                     const unsigned int* __restrict__ isoCnt) {
    if (*isoCnt >= SAT) return;
    cg::grid_group grid = cg::this_grid();
    __shared__ int T[TH * TW];
    const int tid  = threadIdx.x;
    const int blk  = blockIdx.x;
    const int bx   = blk & 7, by = (blk >> 3) & 7, bimg = blk >> 6;
    const int gx0  = bx * CORE - HALO;
    const int gy0  = by * CORE - HALO;
    int* const base0 = bufA + bimg * IMG;
    int* const base1 = bufB + bimg * IMG;

    if (tid < TW) { T[tid] = -1; T[81 * TW + tid] = -1; }
    if (tid < 80) { T[(tid + 1) * TW + 3] = -1; T[(tid + 1) * TW + 84] = -1; }
    for (int u = tid; u < 1600; u += 256) {
        int r = u / 20, c = (u % 20) * 4;
        int gy = gy0 + r, gx = gx0 + c;
        int4 v = (gy >= 0 && gy < 512 && gx >= 0 && gx < 512)
                 ? *(const int4*)(base0 + (gy << 9) + gx)
                 : make_int4(-1, -1, -1, -1);
        *(int4*)&T[(r + 1) * TW + TX0 + c] = v;
    }
    __syncthreads();
    grid.sync();

    const bool active = (tid < 200);
    const int cu = tid % 20, ru = tid / 20;
    const int x0 = cu * 4;
    const int yr = ru * 8;
    int4 O[8];

#define LOAD_ROW(y, V, VL, VR) do {                            \
        const int* _r = &T[((y) + 1) * TW + TX0 + x0];         \
        V  = *(const int4*)_r;                                 \
        VL = _r[-1];                                           \
        VR = _r[4];                                            \
    } while (0)

    for (int r = 0; r < NROUND; ++r) {
        for (int it = 0; it < KIT; ++it) {
            if (active) {
                int4 A, B, C; int Al, Ar, Bl, Br, Cl, Cr;
                LOAD_ROW(yr - 1, A, Al, Ar);
                LOAD_ROW(yr,     B, Bl, Br);
#pragma unroll
                for (int j = 0; j < 8; ++j) {
                    LOAD_ROW(yr + j + 1, C, Cl, Cr);
                    int4 col;
                    col.x = MAX3(A.x, B.x, C.x);
                    col.y = MAX3(A.y, B.y, C.y);
                    col.z = MAX3(A.z, B.z, C.z);
                    col.w = MAX3(A.w, B.w, C.w);
                    int cl = MAX3(Al, Bl, Cl);
                    int cr = MAX3(Ar, Br, Cr);
                    O[j].x = MAX3(cl,    col.x, col.y) | (B.x >> 31);
                    O[j].y = MAX3(col.x, col.y, col.z) | (B.y >> 31);
                    O[j].z = MAX3(col.y, col.z, col.w) | (B.z >> 31);
                    O[j].w = MAX3(col.z, col.w, cr)    | (B.w >> 31);
                    A = B; Al = Bl; Ar = Br;
                    B = C; Bl = Cl; Br = Cr;
                }
            }
            __syncthreads();
            if (active) {
#pragma unroll
                for (int j = 0; j < 8; ++j)
                    *(int4*)&T[(yr + j + 1) * TW + TX0 + x0] = O[j];
            }
            __syncthreads();
        }

        if (r < NROUND - 1) {
            int* dst = (r & 1) ? base1 : base0;
            for (int u = tid; u < 448; u += 256) {
                int lr, lc;
                if (u < 128)      { lr = u >> 4;                lc = u & 15; }
                else if (u < 256) { lr = 56 + ((u - 128) >> 4); lc = u & 15; }
                else { int v = u - 256; lr = 8 + (v >> 2); int s = v & 3; lc = (s < 2) ? s : 12 + s; }
                int4 val = *(const int4*)&T[(HALO + lr + 1) * TW + TX0 + HALO + lc * 4];
                *(int4*)(dst + ((by * CORE + lr) << 9) + bx * CORE + lc * 4) = val;
            }
            __threadfence();
            grid.sync();
            const int* src = (r & 1) ? base1 : base0;
            for (int u = tid; u < 576; u += 256) {
                int lrow, lcu;
                if (u < 160)      { lrow = u / 20;              lcu = u % 20; }
                else if (u < 320) { lrow = 72 + (u - 160) / 20; lcu = u % 20; }
                else { int v = u - 320; lrow = 8 + (v >> 2); int s = v & 3; lcu = (s < 2) ? s : 16 + s; }
                int gy = gy0 + lrow, gx = gx0 + lcu * 4;
                int4 val = (gy >= 0 && gy < 512 && gx >= 0 && gx < 512)
                           ? *(const int4*)(src + (gy << 9) + gx)
                           : make_int4(-1, -1, -1, -1);
                *(int4*)&T[(lrow + 1) * TW + TX0 + lcu * 4] = val;
            }
            __syncthreads();
        } else {
            for (int u = tid; u < 1024; u += 256) {
                int lr = u >> 4, lc = u & 15;
                int4 val = *(const int4*)&T[(HALO + lr + 1) * TW + TX0 + HALO + lc * 4];
                *(int4*)(base0 + ((by * CORE + lr) << 9) + bx * CORE + lc * 4) = val;
            }
        }
    }
#undef LOAD_ROW
}

// ---------- presence bitmap (fallback only) ----------
__global__ __launch_bounds__(256) void k_bits(const int* __restrict__ lab,
                                              unsigned int* __restrict__ bm,
                                              const unsigned int* __restrict__ isoCnt) {
    if (*isoCnt >= SAT) return;
    __shared__ unsigned int sk[1024];
    __shared__ int slot[256];
    const int tid = threadIdx.x;
    unsigned int* rep = bm + (blockIdx.x & (NREP - 1)) * BM_WORDS;
    for (int k = 0; k < 4; ++k) {
        if (k) __syncthreads();
        const int i4 = blockIdx.x * 1024 + k * 256 + tid;
        int4 c = ((const int4*)lab)[i4];
        int pw = __shfl_up(c.w, 1, 64);
        unsigned int prevk;
        if ((tid & 63) == 0) {
            if (i4 == 0) prevk = ~0u;
            else { int pv = lab[i4 * 4 - 1]; prevk = (pv < 0) ? 0u : (unsigned int)pv; }
        } else {
            prevk = (pw < 0) ? 0u : (unsigned int)pw;
        }
        unsigned int k0 = (c.x < 0) ? 0u : (unsigned int)c.x;
        unsigned int k1 = (c.y < 0) ? 0u : (unsigned int)c.y;
        unsigned int k2 = (c.z < 0) ? 0u : (unsigned int)c.z;
        unsigned int k3 = (c.w < 0) ? 0u : (unsigned int)c.w;
        bool c0 = (k0 != prevk), c1 = (k1 != k0), c2 = (k2 != k1), c3 = (k3 != k2);
        sk[0 * 256 + tid] = k0;
        sk[1 * 256 + tid] = k1;
        sk[2 * 256 + tid] = k2;
        sk[3 * 256 + tid] = k3;
        if (c0) slot[k0 & 255] = tid * 4 + 0;
        if (c1) slot[k1 & 255] = tid * 4 + 1;
        if (c2) slot[k2 & 255] = tid * 4 + 2;
        if (c3) slot[k3 & 255] = tid * 4 + 3;
        __syncthreads();
#define SKAT(w) sk[((w) & 3) * 256 + ((w) >> 2)]
        if (c0) { int w = slot[k0 & 255]; if (w != tid * 4 + 0 && SKAT(w) == k0) c0 = false; }
        if (c1) { int w = slot[k1 & 255]; if (w != tid * 4 + 1 && SKAT(w) == k1) c1 = false; }
        if (c2) { int w = slot[k2 & 255]; if (w != tid * 4 + 2 && SKAT(w) == k2) c2 = false; }
        if (c3) { int w = slot[k3 & 255]; if (w != tid * 4 + 3 && SKAT(w) == k3) c3 = false; }
#undef SKAT
#define TSET(kk, cc) if (cc) {                                        \
            unsigned int word = rep[(kk) >> 5];                       \
            if (!((word >> ((kk) & 31)) & 1u))                        \
                atomicOr(&rep[(kk) >> 5], 1u << ((kk) & 31));         \
        }
        TSET(k0, c0); TSET(k1, c1); TSET(k2, c2); TSET(k3, c3);
#undef TSET
    }
}

// ---------- popcount reduce over OR of replicas (fallback only) ----------
__global__ void k_popc(const unsigned int* __restrict__ bm, unsigned int* nuniq, int words,
                       const unsigned int* __restrict__ isoCnt) {
    if (*isoCnt >= SAT) return;
    unsigned int c = 0;
    for (int i = blockIdx.x * blockDim.x + threadIdx.x; i < words; i += gridDim.x * blockDim.x) {
        unsigned int w = 0;
#pragma unroll
        for (int r = 0; r < NREP; ++r) w |= bm[r * BM_WORDS + i];
        c += __popc(w);
    }
    for (int o = 32; o > 0; o >>= 1)
        c += __shfl_down(c, o, 64);
    __shared__ unsigned int sc[4];
    int lane = threadIdx.x & 63, w = threadIdx.x >> 6;
    if (lane == 0) sc[w] = c;
    __syncthreads();
    if (threadIdx.x == 0)
        atomicAdd(nuniq, sc[0] + sc[1] + sc[2] + sc[3]);
}

// ---------- epilogue ----------
__global__ void k_final(const unsigned int* __restrict__ nuniq,
                        const unsigned int* __restrict__ isoCnt,
                        const float* __restrict__ num, const float* __restrict__ den,
                        float* __restrict__ out) {
    float loss = 0.0f;
    for (int b = 0; b < NB; ++b)
        loss += 1.0f - (num[b * 32] + 1.0f) / (den[b * 32] + 1.0f);
    loss *= (1.0f / NB);
    float penalty;
    if (*isoCnt >= SAT) {
        penalty = (float)NB;                    // n_unique >= isoCnt >= 256 => clamp == B exactly
    } else {
        penalty = (float)(*nuniq) / (float)NB;
        if (penalty < 1.0f) penalty = (float)NB;
        penalty = fminf(penalty, (float)NB);
    }
    out[0] = loss * penalty;
}

extern "C" void kernel_launch(void* const* d_in, const int* in_sizes, int n_in,
                              void* d_out, int out_size, void* d_ws, size_t ws_size,
                              hipStream_t stream) {
    const float* predict = (const float*)d_in[0];
    const float* target  = (const float*)d_in[1];
    float* out = (float*)d_out;

    // layout: +0 umax | +4 nuniq | +8 isoCnt | +256 num[512] | +2304 den[512]
    //         +16384 labA (16MB) | labB (16MB) | bm (8MB, disjoint)
    char* ws = (char*)d_ws;
    unsigned int* umax   = (unsigned int*)ws;
    unsigned int* nuniq  = (unsigned int*)(ws + 4);
    unsigned int* isoCnt = (unsigned int*)(ws + 8);
    float* num = (float*)(ws + 256);
    float* den = (float*)(ws + 2304);
    int* labA = (int*)(ws + 16384);
    int* labB = labA + NPIX;
    unsigned int* bm = (unsigned int*)(ws + 16384 + (size_t)2 * NPIX * sizeof(int));

    hipMemsetAsync(ws, 0, 16384, stream);
    hipMemsetAsync(bm, 0, (size_t)NREP * BM_WORDS * sizeof(unsigned int), stream);

    k_max<<<1024, 256, 0, stream>>>((const float4*)predict, umax);
    k_init<<<1024, 256, 0, stream>>>((const float4*)predict, (const float4*)target,
                                     umax, (int4*)labA, num, den);
    k_iso<<<512, 256, 0, stream>>>(labA, isoCnt);

    // fallback propagation (no-op when saturated); final labels land in labA
    void* args[] = { (void*)&labA, (void*)&labB, (void*)&isoCnt };
    hipLaunchCooperativeKernel((void*)k_prop_all, dim3(1024), dim3(256), args, 0, stream);

    k_bits<<<NPIX / 4096, 256, 0, stream>>>(labA, bm, isoCnt);
    k_popc<<<512, 256, 0, stream>>>(bm, nuniq, BM_WORDS, isoCnt);
    k_final<<<1, 1, 0, stream>>>(nuniq, isoCnt, num, den, out);
}